// Round 14
// baseline (215.253 us; speedup 1.0000x reference)
//
#include <hip/hip_runtime.h>
#include <hip/hip_bf16.h>
#include <math.h>

#define DIM 128
#define R1_CHUNK 4096

typedef __attribute__((ext_vector_type(8))) short bf16x8;
typedef __attribute__((ext_vector_type(4))) float f32x4;

// RNE float -> bf16 bits
static __device__ __forceinline__ ushort f2bf(float f) {
    unsigned u = __float_as_uint(f);
    u += 0x7FFFu + ((u >> 16) & 1u);
    return (ushort)(u >> 16);
}

// ---------------- Phase 0a: exclusive scan of lengths -> offsets ----------------
__global__ __launch_bounds__(1024) void scan_kernel(const int* __restrict__ lengths,
                                                    int* __restrict__ offsets, int batch) {
    __shared__ int tsum[1024];
    int tid = threadIdx.x;
    int per = (batch + 1023) >> 10;
    int start = tid * per;
    int s = 0;
    for (int i = 0; i < per; ++i) {
        int idx = start + i;
        if (idx < batch) s += lengths[idx];
    }
    tsum[tid] = s;
    __syncthreads();
    for (int off = 1; off < 1024; off <<= 1) {
        int v = (tid >= off) ? tsum[tid - off] : 0;
        __syncthreads();
        tsum[tid] += v;
        __syncthreads();
    }
    int base = (tid == 0) ? 0 : tsum[tid - 1];
    for (int i = 0; i < per; ++i) {
        int idx = start + i;
        if (idx < batch) { offsets[idx] = base; base += lengths[idx]; }
    }
}

// ---------------- Phase 0b: W1^T bf16, XOR-swizzled image in ws ----------------
__global__ __launch_bounds__(256) void prep_kernel(const float* __restrict__ W1,
                                                   ushort* __restrict__ w1t) {
    int q = blockIdx.x * 256 + threadIdx.x;   // 0..4095
    int n = q >> 5;
    int k4 = q & 31;
    ushort4 w;
    w.x = f2bf(W1[(k4 * 4 + 0) * DIM + n]);
    w.y = f2bf(W1[(k4 * 4 + 1) * DIM + n]);
    w.z = f2bf(W1[(k4 * 4 + 2) * DIM + n]);
    w.w = f2bf(W1[(k4 * 4 + 3) * DIM + n]);
    int c = k4 >> 1;
    *(ushort4*)&w1t[n * 128 + ((c ^ (n & 7)) * 8) + (k4 & 1) * 4] = w;
}

// ---------------- Phase 1: scores = relu(emb @ W1 + b1) @ W2 + b2 --------------
// One-shot block per 128-row tile (grid 6400). W1^T copied linear from ws (it is
// pre-swizzled), bfrags to regs (AGPR-backed), A staged reg->cvt->LDS into the
// SAME 32KB buffer, MFMA + fused epilogue. Inter-block turnover hides latency.
__global__ __launch_bounds__(256, 2) void score_kernel(
        const float* __restrict__ emb, const ushort* __restrict__ w1t,
        const float* __restrict__ b1, const float* __restrict__ W2,
        const float* __restrict__ b2, float* __restrict__ scores, int T) {
    __shared__ ushort sA[128 * 128];   // 32 KB: W1^T image, then A tile

    int tid = threadIdx.x;
    int lane = tid & 63;
    int wv = tid >> 6;
    int lr = lane & 15;
    int lg = lane >> 4;

    // ---- bulk-copy pre-swizzled W1^T image into LDS (16B linear copies)
    #pragma unroll
    for (int i = 0; i < 8; ++i) {
        int q = tid + i * 256;          // 0..2047 16B-chunks
        ((ulonglong2*)sA)[q] = ((const ulonglong2*)w1t)[q];
    }
    __syncthreads();

    // ---- extract B-frags to registers (R3-proven geometry)
    bf16x8 bfrag[8][4];
    #pragma unroll
    for (int ct = 0; ct < 8; ++ct) {
        int n = ct * 16 + lr;
        #pragma unroll
        for (int kc = 0; kc < 4; ++kc) {
            int c = lg + kc * 4;
            bfrag[ct][kc] = *(const bf16x8*)&sA[n * 128 + ((c ^ (n & 7)) * 8)];
        }
    }
    float b1r[8], w2r[8];
    #pragma unroll
    for (int ct = 0; ct < 8; ++ct) {
        b1r[ct] = b1[ct * 16 + lr];
        w2r[ct] = W2[ct * 16 + lr];
    }
    float b2v = b2[0];
    __syncthreads();   // W1^T reads done; sA now holds the A tile

    // ---- stage A tile: 128 rows x 128 k, fp32 -> bf16, swizzled (R3-proven)
    long row0 = (long)blockIdx.x * 128;
    #pragma unroll
    for (int i = 0; i < 16; ++i) {
        int q = tid + i * 256;
        int r = q >> 5;
        int k4 = q & 31;
        long row = row0 + r; if (row > (long)T - 1) row = (long)T - 1;
        float4 v = ((const float4*)emb)[row * 32 + k4];
        ushort4 w;
        w.x = f2bf(v.x); w.y = f2bf(v.y); w.z = f2bf(v.z); w.w = f2bf(v.w);
        int c = k4 >> 1;
        *(ushort4*)&sA[r * 128 + ((c ^ (r & 7)) * 8) + (k4 & 1) * 4] = w;
    }
    __syncthreads();

    // ---- compute: each wave 32 rows (2 x 16-row MFMA tiles)
    #pragma unroll
    for (int rt = 0; rt < 2; ++rt) {
        int rbase = wv * 32 + rt * 16;
        int r = rbase + lr;
        bf16x8 a[4];
        #pragma unroll
        for (int kc = 0; kc < 4; ++kc) {
            int c = lg + kc * 4;
            a[kc] = *(const bf16x8*)&sA[r * 128 + ((c ^ (r & 7)) * 8)];
        }
        f32x4 acc[8];
        #pragma unroll
        for (int ct = 0; ct < 8; ++ct) acc[ct] = (f32x4)(0.f);
        #pragma unroll
        for (int ct = 0; ct < 8; ++ct)
            #pragma unroll
            for (int kc = 0; kc < 4; ++kc)
                acc[ct] = __builtin_amdgcn_mfma_f32_16x16x32_bf16(a[kc], bfrag[ct][kc], acc[ct], 0, 0, 0);

        // epilogue: rowsum of relu(acc+b1)*W2 over the 16 col-lanes; write scores
        #pragma unroll
        for (int reg = 0; reg < 4; ++reg) {
            float s = 0.f;
            #pragma unroll
            for (int ct = 0; ct < 8; ++ct) {
                float h = acc[ct][reg] + b1r[ct];
                h = fmaxf(h, 0.f);
                s = fmaf(h, w2r[ct], s);
            }
            s += __shfl_xor(s, 1, 64);
            s += __shfl_xor(s, 2, 64);
            s += __shfl_xor(s, 4, 64);
            s += __shfl_xor(s, 8, 64);
            if (lr == 0) {
                long grow = row0 + rbase + lg * 4 + reg;
                if (grow < T) scores[grow] = s + b2v;
            }
        }
    }
}

// ---------------- Phase 2a: per-chunk max and sum(exp(s - localmax)) -----------
__global__ __launch_bounds__(256) void reduce1_kernel(const float* __restrict__ scores, int T,
        float* __restrict__ partmax, float* __restrict__ partsum) {
    int tid = threadIdx.x;
    long start = (long)blockIdx.x * R1_CHUNK;
    float v[16];
    float m = -INFINITY;
    #pragma unroll
    for (int i = 0; i < 16; ++i) {
        long idx = start + tid + i * 256;
        v[i] = (idx < T) ? scores[idx] : -INFINITY;
        m = fmaxf(m, v[i]);
    }
    #pragma unroll
    for (int off = 32; off >= 1; off >>= 1) m = fmaxf(m, __shfl_xor(m, off, 64));
    __shared__ float redm[4], reds[4];
    int wave = tid >> 6, lane = tid & 63;
    if (lane == 0) redm[wave] = m;
    __syncthreads();
    float M = fmaxf(fmaxf(redm[0], redm[1]), fmaxf(redm[2], redm[3]));
    float s = 0.f;
    #pragma unroll
    for (int i = 0; i < 16; ++i) s += expf(v[i] - M);
    #pragma unroll
    for (int off = 32; off >= 1; off >>= 1) s += __shfl_xor(s, off, 64);
    if (lane == 0) reds[wave] = s;
    __syncthreads();
    if (tid == 0) {
        partmax[blockIdx.x] = M;
        partsum[blockIdx.x] = reds[0] + reds[1] + reds[2] + reds[3];
    }
}

// ---------------- Phase 2b: combine partials -> global M, 1/S ------------------
__global__ __launch_bounds__(256) void reduce2_kernel(const float* __restrict__ partmax,
        const float* __restrict__ partsum, int nb, float* __restrict__ stats) {
    int tid = threadIdx.x;
    float m = -INFINITY;
    for (int i = tid; i < nb; i += 256) m = fmaxf(m, partmax[i]);
    #pragma unroll
    for (int off = 32; off >= 1; off >>= 1) m = fmaxf(m, __shfl_xor(m, off, 64));
    __shared__ float redm[4], reds[4];
    int wave = tid >> 6, lane = tid & 63;
    if (lane == 0) redm[wave] = m;
    __syncthreads();
    float M = fmaxf(fmaxf(redm[0], redm[1]), fmaxf(redm[2], redm[3]));
    float s = 0.f;
    for (int i = tid; i < nb; i += 256) s += partsum[i] * expf(partmax[i] - M);
    #pragma unroll
    for (int off = 32; off >= 1; off >>= 1) s += __shfl_xor(s, off, 64);
    if (lane == 0) reds[wave] = s;
    __syncthreads();
    if (tid == 0) {
        float S = reds[0] + reds[1] + reds[2] + reds[3];
        stats[0] = M;
        stats[1] = 1.0f / S;
    }
}

// ---------------- Phase 3: pooled[b][d] = sum_j w_j * emb[off+j][d] ------------
__global__ __launch_bounds__(128) void pool_kernel(const float* __restrict__ emb,
        const float* __restrict__ scores, const int* __restrict__ offsets,
        const int* __restrict__ lengths, const float* __restrict__ stats,
        float* __restrict__ out) {
    int b = blockIdx.x;
    int off = offsets[b];
    int len = lengths[b];
    float M = stats[0], invS = stats[1];
    int tid = threadIdx.x;
    __shared__ float sw[128];
    float acc = 0.f;
    for (int base = 0; base < len; base += 128) {
        int n = min(128, len - base);
        __syncthreads();
        if (tid < n) sw[tid] = expf(scores[off + base + tid] - M) * invS;
        __syncthreads();
        for (int j = 0; j < n; ++j)
            acc = fmaf(sw[j], emb[(long)(off + base + j) * DIM + tid], acc);
    }
    out[(long)b * DIM + tid] = acc;
}

extern "C" void kernel_launch(void* const* d_in, const int* in_sizes, int n_in,
                              void* d_out, int out_size, void* d_ws, size_t ws_size,
                              hipStream_t stream) {
    const float* emb     = (const float*)d_in[0];
    const float* W1      = (const float*)d_in[1];
    const float* b1      = (const float*)d_in[2];
    const float* W2      = (const float*)d_in[3];
    const float* b2      = (const float*)d_in[4];
    const int*   lengths = (const int*)d_in[5];
    int T = in_sizes[0] / DIM;
    int batch = in_sizes[5];
    float* out = (float*)d_out;

    // ws: scores[T] | offsets[batch] | partmax[nb1] | partsum[nb1] | stats[2] | w1t[16384 us]
    float* scores  = (float*)d_ws;
    int*   offsets = (int*)(scores + T);
    int nb1 = (T + R1_CHUNK - 1) / R1_CHUNK;
    float* partmax = (float*)(offsets + batch);
    float* partsum = partmax + nb1;
    float* stats   = partsum + nb1;
    ushort* w1t    = (ushort*)(stats + 2);

    scan_kernel<<<1, 1024, 0, stream>>>(lengths, offsets, batch);
    prep_kernel<<<16, 256, 0, stream>>>(W1, w1t);
    score_kernel<<<(T + 127) / 128, 256, 0, stream>>>(emb, w1t, b1, W2, b2, scores, T);
    reduce1_kernel<<<nb1, 256, 0, stream>>>(scores, T, partmax, partsum);
    reduce2_kernel<<<1, 256, 0, stream>>>(partmax, partsum, nb1, stats);
    pool_kernel<<<batch, DIM, 0, stream>>>(emb, scores, offsets, lengths, stats, out);
}